// Round 10
// baseline (125.368 us; speedup 1.0000x reference)
//
#include <hip/hip_runtime.h>
#include <cstdint>
#include <cstddef>

#define BB 128
#define VV 128000
#define TT 4096
#define SS 16                // V-slices per row
#define VR (VV / SS)         // 8000 tokens per slice
#define HW2 (VR / 4)         // 2000 packed LDS words (byte counters)
#define NT 256

typedef float vf4 __attribute__((ext_vector_type(4)));

// Round-20: WAVE SPECIALIZATION. r16 (stream-first, measured r9): total 123.9,
// enforce ~40 us — same as r13's hist-first 43.7. Lesson: phase ORDER doesn't
// matter because the same threads execute both phases serially; total =
// stream + hist + overhead. Fix: waves 0-2 stream the 32KB logits window
// while wave 3 concurrently does hist (private: zero + full-row gen scan +
// 2->3 candidates) — hist latency hides under stream bandwidth. ONE barrier.
// Epilogue = wave 3 only: penalties recomputed from logits (pure function ->
// direct store, no RMW; barrier's vmcnt(0) drain orders the overwrite),
// boosts via atomicAdd (dups accumulate like reference scatter-add; disjoint
// from penalty set cnt>=3 vs cnt==0).
// SENT = 0xFF7F0000 (finite bf16 0xFF7F) — r1/r2 lessons. RINV <=1 ulp.

__device__ __forceinline__ int block_detect(const unsigned char* maskb,
                                            unsigned* det, int tid) {
  if (tid == 0) *det = 0u;
  __syncthreads();
  const uint4* md = (const uint4*)maskb;
  unsigned a = 0u, c = 0u;
#pragma unroll
  for (int k = 0; k < 4; ++k) {          // 256 threads x 4 uint4 = 16 KB scan
    uint4 w = md[tid + k * NT];
    unsigned o = w.x | w.y | w.z | w.w;
    a |= o & 0x000000FFu;                // nonzero byte at offset%4==0
    c |= o & 0xFFFFFF00u;                // nonzero byte at offset%4!=0
  }
  unsigned long long ba = __ballot(a != 0u);
  unsigned long long bc = __ballot(c != 0u);
  if ((tid & 63) == 0) {
    unsigned bits = (ba ? 1u : 0u) | (bc ? 2u : 0u);
    if (bits) atomicOr(det, bits);
  }
  __syncthreads();
  // both byte classes nonzero -> u8; i32/f32/all-zero -> word mode
  return (*det == 3u) ? 1 : 3;
}

template<int ML>
__global__ __launch_bounds__(NT) void enforce_kernel(
    const float* __restrict__ logits,
    const int*  __restrict__ gen,
    const unsigned char* __restrict__ maskb,
    const int*  __restrict__ req,
    float* __restrict__ out,
    int R)
{
  __shared__ unsigned hist[HW2];   // 8 KB byte-packed counts (wave-3 private)
  __shared__ int cand[64];         // 2->3 penalty candidates (E ~ 0.04/block)
  __shared__ unsigned ncand;
  const int tid  = threadIdx.x;
  const int wid  = tid >> 6;
  const int lane = tid & 63;

  // XCD-aware swizzle: all 16 slice-blocks of a row land on one XCD so the
  // row's gen data lives in ONE XCD L2. Wrong mapping only costs locality.
  const int L    = blockIdx.x;           // 2048 blocks
  const int xcd  = L & 7;
  const int q    = L >> 3;
  const int s    = q & (SS - 1);
  const int b    = (q >> 4) * 8 + xcd;   // row in [0,128)
  const int vbase = s * VR;

  int ml = ML;
  if constexpr (ML == -1) {
    __shared__ unsigned det;
    ml = block_detect(maskb, &det, tid);
  }

  const float SENT = __uint_as_float(0xFF7F0000u);
  const float RINV = 1.0f / 1.2f;

  auto forb1 = [&](int t) -> bool {
    if (ml == 1) return maskb[t] != 0;
    return ((const int*)maskb)[t] != 0;  // i32 1 / f32 1.0f both nonzero
  };

  const vf4* lrow = (const vf4*)(logits + (size_t)b * VV + vbase);
  vf4*       orow = (vf4*)(out + (size_t)b * VV + vbase);
  const unsigned* m8  = (const unsigned*)(maskb + vbase);
  const int4*     m32 = (const int4*)((const int*)maskb + vbase);

  auto load_mask = [&](int i) -> unsigned {
    if (ml == 1) return m8[i];
    int4 m = m32[i];
    return (m.x ? 1u : 0u) | (m.y ? 0x100u : 0u) |
           (m.z ? 0x10000u : 0u) | (m.w ? 0x1000000u : 0u);
  };

  if (wid < 3) {
    // ---- waves 0-2: pure masked-copy stream of 2000 vf4 words ----
    for (int i0 = tid; i0 < HW2; i0 += 2 * 192) {   // x2 unroll for MLP
      const int i1 = i0 + 192;
      const bool p1 = (i1 < HW2);
      vf4 x0 = lrow[i0];
      unsigned f0 = load_mask(i0);
      vf4 x1 = {0.f, 0.f, 0.f, 0.f};
      unsigned f1 = 0u;
      if (p1) { x1 = lrow[i1]; f1 = load_mask(i1); }

      vf4 r0, r1;
#pragma unroll
      for (int j = 0; j < 4; ++j)
        r0[j] = ((f0 >> (j * 8)) & 0xFFu) ? SENT : x0[j];
      orow[i0] = r0;
      if (p1) {
#pragma unroll
        for (int j = 0; j < 4; ++j)
          r1[j] = ((f1 >> (j * 8)) & 0xFFu) ? SENT : x1[j];
        orow[i1] = r1;
      }
    }
  } else {
    // ---- wave 3: private hist (zero -> scan -> candidates); no cross-wave
    // LDS access until the barrier, so no extra sync needed. ncand init is
    // same-wave program-ordered before the atomics. ----
    for (int i = lane; i < HW2; i += 64) hist[i] = 0u;
    if (lane == 0) ncand = 0u;

    const int4* grow = (const int4*)(gen + b * TT);
    for (int i = lane; i < TT / 4; i += 64) {       // 16 iterations
      int4 g = grow[i];
      const int t4[4] = {g.x, g.y, g.z, g.w};
#pragma unroll
      for (int j = 0; j < 4; ++j) {
        const int t = t4[j];
        unsigned d = (unsigned)(t - vbase);
        if (d < (unsigned)VR) {
          const unsigned sh = (d & 3u) * 8u;
          unsigned old = atomicAdd(&hist[d >> 2], 1u << sh);
          if (((old >> sh) & 0xFFu) == 2u) {        // unique 2->3 catch
            unsigned k = atomicAdd(&ncand, 1u);
            if (k < 64u) cand[k] = t;
          }
        }
      }
    }
  }
  __syncthreads();   // drains stream stores (vmcnt 0); hist complete

  if (wid == 3) {
    // ---- penalties: direct store recomputed from logits (pure function;
    // overwrite of the streamed value is ordered by the barrier drain) ----
    const unsigned nc = ncand < 64u ? ncand : 64u;
    for (unsigned k = lane; k < nc; k += 64) {
      const int t = cand[k];
      if (!forb1(t)) {                   // reference skips -inf slots
        float v = logits[(size_t)b * VV + t];      // L2-hot (just streamed)
        out[(size_t)b * VV + t] = (v > 0.0f) ? v * RINV : v * 1.2f;
      }
    }
    // ---- boosts: req tokens with cnt==0 & allowed; dup entries accumulate
    // via float atomicAdd like the reference .at[].add; disjoint from above ----
    for (int r = lane; r < R; r += 64) {
      const int t = req[r];
      unsigned d = (unsigned)(t - vbase);
      if (d < (unsigned)VR) {
        unsigned cnt = (hist[d >> 2] >> ((d & 3u) * 8u)) & 0xFFu;
        if (cnt == 0u && !forb1(t))
          atomicAdd(out + (size_t)b * VV + t, 5.0f);
      }
    }
  }
}

extern "C" void kernel_launch(void* const* d_in, const int* in_sizes, int n_in,
                              void* d_out, int out_size, void* d_ws, size_t ws_size,
                              hipStream_t stream) {
  const float* logits = (const float*)d_in[0];
  const int*   gen    = (const int*)d_in[1];
  const unsigned char* maskb = (const unsigned char*)d_in[2];
  const int*   req    = (const int*)d_in[3];
  float* out = (float*)d_out;

  // R: 64 whether in_sizes reports elements (64) or bytes (256)
  int R = in_sizes[3];
  if (R >= 256 && (R & 3) == 0) R >>= 2;

  // mask layout: decide host-side when in_sizes reports BYTES (identified via
  // logits size); otherwise fall back to on-device per-block detect.
  int ml;
  if (in_sizes[0] == BB * VV * 4) {             // bytes mode (65,536,000)
    ml = (in_sizes[2] == VV) ? 1 : 3;           // 128000 -> u8 ; 512000 -> 32-bit
  } else {
    ml = -1;
  }

  const int G = BB * SS;                        // 2048 blocks, 8/CU
  if (ml == 1)      enforce_kernel<1><<<G, NT, 0, stream>>>(logits, gen, maskb, req, out, R);
  else if (ml == 3) enforce_kernel<3><<<G, NT, 0, stream>>>(logits, gen, maskb, req, out, R);
  else              enforce_kernel<-1><<<G, NT, 0, stream>>>(logits, gen, maskb, req, out, R);
}